// Round 10
// baseline (225.863 us; speedup 1.0000x reference)
//
#include <hip/hip_runtime.h>

#define GG 64
#define HH 16
#define KK 64   // H*C
#define S_SUB 8

__device__ __forceinline__ float bf2f(unsigned short u){
  return __uint_as_float(((unsigned)u) << 16);
}
__device__ __forceinline__ unsigned short f2bf(float f){
  unsigned u = __float_as_uint(f);
  unsigned r = u + 0x7fffu + ((u >> 16) & 1u);   // round-to-nearest-even
  return (unsigned short)(r >> 16);
}

// nontemporal int2 helpers via 64-bit integer reinterpret
__device__ __forceinline__ void nt_store_i2(int2 v, int2* p){
  long long w = ((unsigned long long)(unsigned)v.y << 32) | (unsigned)v.x;
  __builtin_nontemporal_store(w, (long long*)p);
}
__device__ __forceinline__ int2 nt_load_i2(const int2* p){
  long long w = __builtin_nontemporal_load((const long long*)p);
  int2 r; r.x = (int)(unsigned)(w & 0xffffffffu); r.y = (int)(unsigned)(w >> 32);
  return r;
}

// ---------- zero workspace (int4 grid-stride) + group bounds fused ----------
__global__ void k_zero(int4* __restrict__ p, int nInt4,
                       const int* __restrict__ batch, int N, int* __restrict__ goff){
  int t = blockIdx.x*blockDim.x + threadIdx.x;
  for (int i = t; i < nInt4; i += gridDim.x*blockDim.x)
    p[i] = make_int4(0,0,0,0);
  if (blockIdx.x == 0 && threadIdx.x <= GG){
    int g = threadIdx.x;
    int lo = 0, hi = N;
    while (lo < hi){ int mid = (lo+hi) >> 1; if (batch[mid] < g) lo = mid+1; else hi = mid; }
    goff[g] = lo;
  }
}

// ---------- CSR build ----------

__global__ void k_count_rank(const int* __restrict__ ei, int* deg, int* __restrict__ rank, int E){
  int e = blockIdx.x*blockDim.x + threadIdx.x;
  if (e < E) rank[e] = atomicAdd(&deg[ei[E + e]], 1);
}

__global__ void k_scan1(const int* __restrict__ deg, int* __restrict__ bsum, int N){
  int base = blockIdx.x*1024;
  int lim = min(base + 1024, N);
  int s = 0;
  for (int i = base + (int)threadIdx.x; i < lim; i += 256) s += deg[i];
  #pragma unroll
  for (int ofs = 32; ofs >= 1; ofs >>= 1) s += __shfl_down(s, ofs, 64);
  __shared__ int ws[4];
  int lane = threadIdx.x & 63, wv = threadIdx.x >> 6;
  if (lane == 0) ws[wv] = s;
  __syncthreads();
  if (threadIdx.x == 0) bsum[blockIdx.x] = ws[0] + ws[1] + ws[2] + ws[3];
}

__global__ void __launch_bounds__(1024)
k_scan2(int* __restrict__ bsum, int* __restrict__ row_start_N, int NB){
  int t = threadIdx.x;
  int v = (t < NB) ? bsum[t] : 0;
  int lane = t & 63, wv = t >> 6;
  int val = v;
  #pragma unroll
  for (int ofs = 1; ofs < 64; ofs <<= 1){
    int tt = __shfl_up(val, ofs, 64);
    if (lane >= ofs) val += tt;
  }
  __shared__ int ws[16];
  if (lane == 63) ws[wv] = val;
  __syncthreads();
  if (t == 0){
    int run = 0;
    #pragma unroll
    for (int w = 0; w < 16; ++w){ int tmp = ws[w]; ws[w] = run; run += tmp; }
  }
  __syncthreads();
  int excl = ws[wv] + val - v;
  if (t < NB) bsum[t] = excl;
  if (t == NB - 1) *row_start_N = excl + v;
}

__global__ void k_scan3(const int* __restrict__ deg, const int* __restrict__ bsum,
                        int* __restrict__ row_start, int N){
  int b = blockIdx.x;
  int base = b*1024 + (int)threadIdx.x*4;
  int d0 = (base+0 < N) ? deg[base+0] : 0;
  int d1 = (base+1 < N) ? deg[base+1] : 0;
  int d2 = (base+2 < N) ? deg[base+2] : 0;
  int d3 = (base+3 < N) ? deg[base+3] : 0;
  int s = d0 + d1 + d2 + d3;
  int lane = threadIdx.x & 63, wv = threadIdx.x >> 6;
  int val = s;
  #pragma unroll
  for (int ofs = 1; ofs < 64; ofs <<= 1){
    int tt = __shfl_up(val, ofs, 64);
    if (lane >= ofs) val += tt;
  }
  __shared__ int ws[4];
  if (lane == 63) ws[wv] = val;
  __syncthreads();
  if (threadIdx.x == 0){
    int run = 0;
    #pragma unroll
    for (int w = 0; w < 4; ++w){ int tmp = ws[w]; ws[w] = run; run += tmp; }
  }
  __syncthreads();
  int pre = bsum[b] + ws[wv] + val - s;
  if (base+0 < N){ row_start[base+0] = pre; pre += d0; }
  if (base+1 < N){ row_start[base+1] = pre; pre += d1; }
  if (base+2 < N){ row_start[base+2] = pre; pre += d2; }
  if (base+3 < N){ row_start[base+3] = pre; }
}

__global__ void k_scatter(const int* __restrict__ ei, const float* __restrict__ ea,
                          const int* __restrict__ row_start, const int* __restrict__ rank,
                          int2* __restrict__ csr_se, int E){
  int e = blockIdx.x*blockDim.x + threadIdx.x;
  if (e >= E) return;
  int d = ei[E + e];
  int pos = row_start[d] + rank[e];
  nt_store_i2(make_int2(ei[e], __float_as_int(ea[e])), &csr_se[pos]);
}

// ---------- GAT: 4 lanes/node, 4 heads per lane, 4-unrolled edge loop ----------
__global__ void k_gat(const float* __restrict__ x, const int* __restrict__ row_start,
                      const int2* __restrict__ cse,
                      const float* __restrict__ Wl, const float* __restrict__ bl,
                      const float* __restrict__ Wr, const float* __restrict__ br,
                      const float* __restrict__ We, const float* __restrict__ att,
                      const float* __restrict__ gat_bias,
                      float* __restrict__ h, int N){
  int t = blockIdx.x*blockDim.x + threadIdx.x;
  int n   = t >> 2;
  int sub = t & 3;
  if (n >= N) return;
  float xd = x[n];
  float wl[16], we[16], at[16], pre[16];
  int k0 = sub*16;
  #pragma unroll
  for (int i = 0; i < 16; ++i){
    int k = k0 + i;
    wl[i] = Wl[k]; we[i] = We[k]; at[i] = att[k];
    pre[i] = bl[k] + fmaf(xd, Wr[k], br[k]);
  }
  int e0 = row_start[n], e1 = row_start[n+1];
  float m[4]  = {-3.4e38f,-3.4e38f,-3.4e38f,-3.4e38f};
  float den[4] = {0,0,0,0}, S1[4] = {0,0,0,0};
  float asum = 0.f;

#define PROC(XS, EAV)                                                        \
  { float xs_ = (XS), ea_ = (EAV);                                           \
    _Pragma("unroll")                                                        \
    for (int hi2 = 0; hi2 < 4; ++hi2){                                       \
      float sc = 0.f;                                                        \
      _Pragma("unroll")                                                      \
      for (int c = 0; c < 4; ++c){                                           \
        int i = hi2*4 + c;                                                   \
        float tt = fmaf(xs_, wl[i], fmaf(ea_, we[i], pre[i]));               \
        tt = (tt > 0.f) ? tt : 0.2f*tt;                                      \
        sc = fmaf(tt, at[i], sc);                                            \
      }                                                                      \
      float nm = fmaxf(m[hi2], sc);                                          \
      float corr = __expf(m[hi2] - nm);                                      \
      float a    = __expf(sc - nm);                                          \
      den[hi2] = den[hi2]*corr + a;                                          \
      S1[hi2]  = S1[hi2] *corr + a*xs_;                                      \
      m[hi2] = nm; } }

  int e = e0;
  for (; e + 3 < e1; e += 4){
    int2 p0 = nt_load_i2(&cse[e]);
    int2 p1 = nt_load_i2(&cse[e+1]);
    int2 p2 = nt_load_i2(&cse[e+2]);
    int2 p3 = nt_load_i2(&cse[e+3]);
    float xs0 = x[p0.x], xs1 = x[p1.x], xs2 = x[p2.x], xs3 = x[p3.x];
    float ea0 = __int_as_float(p0.y), ea1 = __int_as_float(p1.y);
    float ea2 = __int_as_float(p2.y), ea3 = __int_as_float(p3.y);
    asum += (ea0 + ea1) + (ea2 + ea3);
    PROC(xs0, ea0);
    PROC(xs1, ea1);
    PROC(xs2, ea2);
    PROC(xs3, ea3);
  }
  for (; e < e1; ++e){
    int2 p0 = cse[e];
    float xs0 = x[p0.x], ea0 = __int_as_float(p0.y);
    asum += ea0;
    PROC(xs0, ea0);
  }
  { // self loop
    float degf = (float)(e1 - e0);
    float eav = asum / fmaxf(degf, 1.0f);
    PROC(xd, eav);
  }
#undef PROC
  #pragma unroll
  for (int hi2 = 0; hi2 < 4; ++hi2){
    float r = S1[hi2] / den[hi2];
    float4 o;
    #pragma unroll
    for (int c = 0; c < 4; ++c){
      int i = hi2*4 + c, k = k0 + i;
      float v = fmaxf(fmaf(wl[i], r, bl[k] + gat_bias[k]), 0.f);
      ((float*)&o)[c] = v;
    }
    *(float4*)(h + (size_t)n*KK + k0 + hi2*4) = o;
  }
}

// ---------- GroupNorm stats: (G x S_SUB) blocks, partial + atomic combine ----------
__global__ void k_gstats_part(const float* __restrict__ h, const int* __restrict__ goff,
                              float* __restrict__ gsum, float* __restrict__ gsum2){
  int g = blockIdx.x, sb = blockIdx.y;
  int s = goff[g], epos = goff[g+1];
  int k = threadIdx.x & 63, slice = threadIdx.x >> 6;
  float sum = 0.f, sum2 = 0.f;
  for (int n = s + sb*4 + slice; n < epos; n += S_SUB*4){
    float v = h[(size_t)n*KK + k];
    sum += v; sum2 += v*v;
  }
  __shared__ float ls[4][KK], ls2[4][KK];
  ls[slice][k] = sum; ls2[slice][k] = sum2;
  __syncthreads();
  if (slice == 0){
    float a  = ls[0][k]+ls[1][k]+ls[2][k]+ls[3][k];
    float b2 = ls2[0][k]+ls2[1][k]+ls2[2][k]+ls2[3][k];
    atomicAdd(&gsum[g*KK + k], a);
    atomicAdd(&gsum2[g*KK + k], b2);
  }
}

// ---------- normalize (fused coefficients) + bf16 copy, float4 ----------
__global__ void k_norm(float* __restrict__ h, unsigned short* __restrict__ hb,
                       const int* __restrict__ batch,
                       const float* __restrict__ gsum, const float* __restrict__ gsum2,
                       const int* __restrict__ goff,
                       const float* __restrict__ gn_w, const float* __restrict__ gn_b,
                       const float* __restrict__ gn_ms, int N){
  int t = blockIdx.x*blockDim.x + threadIdx.x;
  if (t >= N*16) return;
  int n = t >> 4, q = t & 15;
  int b = batch[n];
  float c = fmaxf((float)(goff[b+1] - goff[b]), 1.0f);
  float inv = 1.0f / c;
  float4 hv = *(float4*)(h + (size_t)n*KK + q*4);
  float ov[4];
  #pragma unroll
  for (int i = 0; i < 4; ++i){
    int k = q*4 + i;
    float mean = gsum[b*KK + k]*inv;
    float eh2  = gsum2[b*KK + k]*inv;
    float ms = gn_ms[k];
    float var = eh2 - 2.f*ms*mean*mean + ms*ms*mean*mean;
    float sc = gn_w[k] * __frsqrt_rn(var + 1e-5f);
    float sh = gn_b[k] - sc*mean*ms;
    ov[i] = fmaf(sc, ((float*)&hv)[i], sh);
  }
  *(float4*)(h + (size_t)n*KK + q*4) = make_float4(ov[0], ov[1], ov[2], ov[3]);
  ushort4 bv;
  bv.x = f2bf(ov[0]); bv.y = f2bf(ov[1]); bv.z = f2bf(ov[2]); bv.w = f2bf(ov[3]);
  *(ushort4*)(hb + (size_t)n*KK + q*4) = bv;
}

// ---------- SAGE: ushort4 gather, 8-unrolled, 16 nodes / 256-thread block ----------
__global__ void k_sage(const float* __restrict__ h, const unsigned short* __restrict__ hb,
                       const int* __restrict__ row_start, const int2* __restrict__ cse,
                       const float* __restrict__ Wl, const float* __restrict__ bln,
                       const float* __restrict__ Wr,
                       float* __restrict__ h2, int N){
  __shared__ float snm[16][KK], shn[16][KK];
  const ushort4* hb4 = (const ushort4*)hb;
  int tid = threadIdx.x;
  int u = tid >> 4;
  int q = tid & 15;
  int n = blockIdx.x*16 + u;
  if (n < N){
    int e0 = row_start[n], e1 = row_start[n+1];
    float a0=0.f,a1=0.f,a2=0.f,a3=0.f;
    float b0=0.f,b1=0.f,b2=0.f,b3=0.f;
    int e = e0;
    for (; e + 7 < e1; e += 8){
      int s0 = nt_load_i2(&cse[e]).x;
      int s1 = nt_load_i2(&cse[e+1]).x;
      int s2 = nt_load_i2(&cse[e+2]).x;
      int s3 = nt_load_i2(&cse[e+3]).x;
      int s4 = nt_load_i2(&cse[e+4]).x;
      int s5 = nt_load_i2(&cse[e+5]).x;
      int s6 = nt_load_i2(&cse[e+6]).x;
      int s7 = nt_load_i2(&cse[e+7]).x;
      ushort4 v0 = hb4[(size_t)s0*16 + q];
      ushort4 v1 = hb4[(size_t)s1*16 + q];
      ushort4 v2 = hb4[(size_t)s2*16 + q];
      ushort4 v3 = hb4[(size_t)s3*16 + q];
      ushort4 v4 = hb4[(size_t)s4*16 + q];
      ushort4 v5 = hb4[(size_t)s5*16 + q];
      ushort4 v6 = hb4[(size_t)s6*16 + q];
      ushort4 v7 = hb4[(size_t)s7*16 + q];
      a0 += bf2f(v0.x); a1 += bf2f(v0.y); a2 += bf2f(v0.z); a3 += bf2f(v0.w);
      b0 += bf2f(v1.x); b1 += bf2f(v1.y); b2 += bf2f(v1.z); b3 += bf2f(v1.w);
      a0 += bf2f(v2.x); a1 += bf2f(v2.y); a2 += bf2f(v2.z); a3 += bf2f(v2.w);
      b0 += bf2f(v3.x); b1 += bf2f(v3.y); b2 += bf2f(v3.z); b3 += bf2f(v3.w);
      a0 += bf2f(v4.x); a1 += bf2f(v4.y); a2 += bf2f(v4.z); a3 += bf2f(v4.w);
      b0 += bf2f(v5.x); b1 += bf2f(v5.y); b2 += bf2f(v5.z); b3 += bf2f(v5.w);
      a0 += bf2f(v6.x); a1 += bf2f(v6.y); a2 += bf2f(v6.z); a3 += bf2f(v6.w);
      b0 += bf2f(v7.x); b1 += bf2f(v7.y); b2 += bf2f(v7.z); b3 += bf2f(v7.w);
    }
    for (; e < e1; ++e){
      ushort4 v0 = hb4[(size_t)cse[e].x*16 + q];
      a0 += bf2f(v0.x); a1 += bf2f(v0.y); a2 += bf2f(v0.z); a3 += bf2f(v0.w);
    }
    float dg = fmaxf((float)(e1 - e0), 1.0f);
    float inv = 1.0f/dg;
    float4 nm = make_float4((a0+b0)*inv, (a1+b1)*inv, (a2+b2)*inv, (a3+b3)*inv);
    *(float4*)&snm[u][q*4] = nm;
    *(float4*)&shn[u][q*4] = *(const float4*)(h + (size_t)n*KK + q*4);
  }
  __syncthreads();
  int j = tid & 63, u0 = tid >> 6;
  float acc[4];
  #pragma unroll
  for (int p = 0; p < 4; ++p) acc[p] = bln[j];
  for (int k = 0; k < KK; ++k){
    float wlv = Wl[k*KK + j], wrv = Wr[k*KK + j];
    #pragma unroll
    for (int p = 0; p < 4; ++p){
      int un = u0 + p*4;
      acc[p] = fmaf(snm[un][k], wlv, acc[p]);
      acc[p] = fmaf(shn[un][k], wrv, acc[p]);
    }
  }
  #pragma unroll
  for (int p = 0; p < 4; ++p){
    int un = u0 + p*4;
    int nn = blockIdx.x*16 + un;
    if (nn < N) h2[(size_t)nn*KK + j] = fmaxf(acc[p], 0.f);
  }
}

// ---------- pooling: (G x S_SUB) partial blocks + atomic combine ----------
__global__ void k_pool_part(const float* __restrict__ h2, const int* __restrict__ goff,
                            unsigned* __restrict__ gmaxu, float* __restrict__ gsumP){
  int g = blockIdx.x, sb = blockIdx.y;
  int s = goff[g], epos = goff[g+1];
  int k = threadIdx.x & 63, slice = threadIdx.x >> 6;
  float mx = 0.f, sm = 0.f;   // h2 >= 0
  for (int n = s + sb*4 + slice; n < epos; n += S_SUB*4){
    float v = h2[(size_t)n*KK + k];
    mx = fmaxf(mx, v); sm += v;
  }
  __shared__ float lm[4][KK], lsum[4][KK];
  lm[slice][k] = mx; lsum[slice][k] = sm;
  __syncthreads();
  if (slice == 0){
    float m2 = fmaxf(fmaxf(lm[0][k], lm[1][k]), fmaxf(lm[2][k], lm[3][k]));
    float s2 = lsum[0][k]+lsum[1][k]+lsum[2][k]+lsum[3][k];
    atomicMax(&gmaxu[g*KK + k], __float_as_uint(m2));
    atomicAdd(&gsumP[g*KK + k], s2);
  }
}

// ---------- dense layers ----------

__global__ void k_fc1(const unsigned* __restrict__ gmaxu, const float* __restrict__ gsumP,
                      const int* __restrict__ goff,
                      const float* __restrict__ W, const float* __restrict__ b,
                      float* __restrict__ out){
  __shared__ float sin[128];
  int g = blockIdx.y, jt = blockIdx.x;
  int tid = threadIdx.x;
  if (tid < 128){
    float c = fmaxf((float)(goff[g+1] - goff[g]), 1.0f);
    sin[tid] = (tid < 64) ? __uint_as_float(gmaxu[g*64 + tid])
                          : gsumP[g*64 + (tid-64)] / c;
  }
  __syncthreads();
  int j = jt*256 + tid;
  float acc = b[j];
  #pragma unroll 16
  for (int k = 0; k < 128; ++k)
    acc = fmaf(sin[k], W[(size_t)k*2048 + j], acc);
  out[(size_t)g*2048 + j] = fmaxf(acc, 0.f);
}

__global__ void k_fc2a(const float* __restrict__ in, const float* __restrict__ W,
                       float* __restrict__ partial){
  __shared__ float sin[64][128];
  int jt = blockIdx.x, ks = blockIdx.y;
  int k0 = ks*128;
  int tid = threadIdx.x;
  for (int idx = tid; idx < 64*128; idx += 256){
    int g = idx >> 7, k = idx & 127;
    sin[g][k] = in[(size_t)g*2048 + k0 + k];
  }
  __syncthreads();
  int j = tid & 63, gs = tid >> 6;
  const float* Wp = W + (size_t)k0*1024 + jt*64 + j;
  float acc[16];
  #pragma unroll
  for (int p = 0; p < 16; ++p) acc[p] = 0.f;
  for (int k = 0; k < 128; ++k){
    float w = Wp[(size_t)k*1024];
    #pragma unroll
    for (int p = 0; p < 16; ++p)
      acc[p] = fmaf(sin[gs*16 + p][k], w, acc[p]);
  }
  #pragma unroll
  for (int p = 0; p < 16; ++p){
    int g = gs*16 + p;
    partial[((size_t)ks*64 + g)*1024 + jt*64 + j] = acc[p];
  }
}

__global__ void k_fc2red(const float* __restrict__ partial, const float* __restrict__ b,
                         float* __restrict__ out){
  int i = blockIdx.x*blockDim.x + threadIdx.x;
  int g = i >> 10, j = i & 1023;
  float s = b[j];
  #pragma unroll
  for (int ks = 0; ks < 16; ++ks)
    s += partial[((size_t)ks*64 + g)*1024 + j];
  out[i] = fmaxf(s, 0.f);
}

__global__ void k_fc3(const float* __restrict__ in, const float* __restrict__ W,
                      const float* __restrict__ b, float* __restrict__ out, int nOut){
  int w = (blockIdx.x*blockDim.x + threadIdx.x) >> 6;
  int lane = threadIdx.x & 63;
  if (w >= GG*nOut) return;
  int g = w / nOut, j = w - g*nOut;
  const float* row = in + (size_t)g*1024;
  float acc = 0.f;
  #pragma unroll
  for (int k = lane; k < 1024; k += 64)
    acc = fmaf(row[k], W[(size_t)k*nOut + j], acc);
  #pragma unroll
  for (int ofs = 32; ofs >= 1; ofs >>= 1)
    acc += __shfl_down(acc, ofs, 64);
  if (lane == 0) out[w] = acc + b[j];
}

extern "C" void kernel_launch(void* const* d_in, const int* in_sizes, int n_in,
                              void* d_out, int out_size, void* d_ws, size_t ws_size,
                              hipStream_t stream) {
  const float* x        = (const float*)d_in[0];
  const int*   ei       = (const int*)d_in[1];
  const float* ea       = (const float*)d_in[2];
  const int*   batch    = (const int*)d_in[3];
  const float* Wl       = (const float*)d_in[4];
  const float* bl       = (const float*)d_in[5];
  const float* Wr       = (const float*)d_in[6];
  const float* br       = (const float*)d_in[7];
  const float* We       = (const float*)d_in[8];
  const float* att      = (const float*)d_in[9];
  const float* gat_bias = (const float*)d_in[10];
  const float* gn_w     = (const float*)d_in[11];
  const float* gn_b     = (const float*)d_in[12];
  const float* gn_ms    = (const float*)d_in[13];
  const float* sage_Wl  = (const float*)d_in[14];
  const float* sage_bl  = (const float*)d_in[15];
  const float* sage_Wr  = (const float*)d_in[16];
  const float* fc1_W    = (const float*)d_in[17];
  const float* fc1_b    = (const float*)d_in[18];
  const float* fc2_W    = (const float*)d_in[19];
  const float* fc2_b    = (const float*)d_in[20];
  const float* fc3_W    = (const float*)d_in[21];
  const float* fc3_b    = (const float*)d_in[22];

  const int N = in_sizes[0];
  const int E = in_sizes[1] / 2;
  const int NB = (N + 1023) / 1024;

  char* ws = (char*)d_ws;
  size_t off = 0;
  auto alloc = [&](size_t bytes){ void* p = ws + off; off += (bytes + 255) & ~(size_t)255; return p; };

  int*      deg_i  = (int*)alloc((size_t)N*4);        // zeroed
  float*    gsum   = (float*)alloc(GG*KK*4);          // zeroed
  float*    gsum2  = (float*)alloc(GG*KK*4);          // zeroed
  unsigned* gmaxu  = (unsigned*)alloc(GG*KK*4);       // zeroed
  float*    gsumP  = (float*)alloc(GG*KK*4);          // zeroed
  size_t zero_bytes = off;                            // 256-aligned => /16 exact
  int*   rank      = (int*)alloc((size_t)E*4);
  int*   bsum      = (int*)alloc((size_t)NB*4);
  int*   row_start = (int*)alloc((size_t)(N+1)*4);
  int*   goff      = (int*)alloc((GG+1)*4);
  int2*  csr_se    = (int2*)alloc((size_t)E*8);
  float* h         = (float*)alloc((size_t)N*KK*4);
  unsigned short* hb = (unsigned short*)alloc((size_t)N*KK*2);
  float* h2        = (float*)alloc((size_t)N*KK*4);
  float* out1      = (float*)alloc((size_t)GG*2048*4);
  float* out2      = (float*)alloc((size_t)GG*1024*4);
  float* partial   = (float*)alloc((size_t)16*GG*1024*4);
  (void)ws_size; (void)n_in; (void)out_size;

  const int B = 256;
  {
    int nInt4 = (int)(zero_bytes >> 4);
    int blocks = min((nInt4 + B - 1)/B, 256);
    k_zero <<<blocks, B, 0, stream>>>((int4*)d_ws, nInt4, batch, N, goff);
  }
  k_count_rank<<<(E+B-1)/B, B, 0, stream>>>(ei, deg_i, rank, E);
  k_scan1  <<<NB, B, 0, stream>>>(deg_i, bsum, N);
  k_scan2  <<<1, 1024, 0, stream>>>(bsum, row_start + N, NB);
  k_scan3  <<<NB, B, 0, stream>>>(deg_i, bsum, row_start, N);
  k_scatter<<<(E+B-1)/B, B, 0, stream>>>(ei, ea, row_start, rank, csr_se, E);
  k_gat    <<<((size_t)N*4+B-1)/B, B, 0, stream>>>(x, row_start, csr_se,
                                                   Wl, bl, Wr, br, We, att, gat_bias, h, N);
  {
    dim3 grid(GG, S_SUB);
    k_gstats_part<<<grid, 256, 0, stream>>>(h, goff, gsum, gsum2);
  }
  k_norm   <<<((size_t)N*16+B-1)/B, B, 0, stream>>>(h, hb, batch, gsum, gsum2, goff,
                                                    gn_w, gn_b, gn_ms, N);
  k_sage   <<<(N+15)/16, B, 0, stream>>>(h, hb, row_start, csr_se, sage_Wl, sage_bl, sage_Wr, h2, N);
  {
    dim3 grid(GG, S_SUB);
    k_pool_part<<<grid, 256, 0, stream>>>(h2, goff, gmaxu, gsumP);
  }
  {
    dim3 grid(8, GG);
    k_fc1  <<<grid, 256, 0, stream>>>(gmaxu, gsumP, goff, fc1_W, fc1_b, out1);
  }
  {
    dim3 grid(16, 16);
    k_fc2a <<<grid, 256, 0, stream>>>(out1, fc2_W, partial);
  }
  k_fc2red <<<(GG*1024+B-1)/B, B, 0, stream>>>(partial, fc2_b, out2);
  k_fc3    <<<(GG*3*64+B-1)/B, B, 0, stream>>>(out2, fc3_W, fc3_b, (float*)d_out, 3);
}

// Round 11
// 191.681 us; speedup vs baseline: 1.1783x; 1.1783x over previous
//
#include <hip/hip_runtime.h>

#define GG 64
#define HH 16
#define KK 64   // H*C
#define S_SUB 8

__device__ __forceinline__ float bf2f(unsigned short u){
  return __uint_as_float(((unsigned)u) << 16);
}
__device__ __forceinline__ unsigned short f2bf(float f){
  unsigned u = __float_as_uint(f);
  unsigned r = u + 0x7fffu + ((u >> 16) & 1u);   // round-to-nearest-even
  return (unsigned short)(r >> 16);
}

// ---------- zero workspace (int4 grid-stride) + group bounds fused ----------
__global__ void k_zero(int4* __restrict__ p, int nInt4,
                       const int* __restrict__ batch, int N, int* __restrict__ goff){
  int t = blockIdx.x*blockDim.x + threadIdx.x;
  for (int i = t; i < nInt4; i += gridDim.x*blockDim.x)
    p[i] = make_int4(0,0,0,0);
  if (blockIdx.x == 0 && threadIdx.x <= GG){
    int g = threadIdx.x;
    int lo = 0, hi = N;
    while (lo < hi){ int mid = (lo+hi) >> 1; if (batch[mid] < g) lo = mid+1; else hi = mid; }
    goff[g] = lo;
  }
}

// ---------- CSR build ----------

__global__ void k_count_rank(const int* __restrict__ ei, int* deg, int* __restrict__ rank, int E){
  int e = blockIdx.x*blockDim.x + threadIdx.x;
  if (e < E) rank[e] = atomicAdd(&deg[ei[E + e]], 1);
}

__global__ void k_scan1(const int* __restrict__ deg, int* __restrict__ bsum, int N){
  int base = blockIdx.x*1024;
  int lim = min(base + 1024, N);
  int s = 0;
  for (int i = base + (int)threadIdx.x; i < lim; i += 256) s += deg[i];
  #pragma unroll
  for (int ofs = 32; ofs >= 1; ofs >>= 1) s += __shfl_down(s, ofs, 64);
  __shared__ int ws[4];
  int lane = threadIdx.x & 63, wv = threadIdx.x >> 6;
  if (lane == 0) ws[wv] = s;
  __syncthreads();
  if (threadIdx.x == 0) bsum[blockIdx.x] = ws[0] + ws[1] + ws[2] + ws[3];
}

__global__ void __launch_bounds__(1024)
k_scan2(int* __restrict__ bsum, int* __restrict__ row_start_N, int NB){
  int t = threadIdx.x;
  int v = (t < NB) ? bsum[t] : 0;
  int lane = t & 63, wv = t >> 6;
  int val = v;
  #pragma unroll
  for (int ofs = 1; ofs < 64; ofs <<= 1){
    int tt = __shfl_up(val, ofs, 64);
    if (lane >= ofs) val += tt;
  }
  __shared__ int ws[16];
  if (lane == 63) ws[wv] = val;
  __syncthreads();
  if (t == 0){
    int run = 0;
    #pragma unroll
    for (int w = 0; w < 16; ++w){ int tmp = ws[w]; ws[w] = run; run += tmp; }
  }
  __syncthreads();
  int excl = ws[wv] + val - v;
  if (t < NB) bsum[t] = excl;
  if (t == NB - 1) *row_start_N = excl + v;
}

__global__ void k_scan3(const int* __restrict__ deg, const int* __restrict__ bsum,
                        int* __restrict__ row_start, int N){
  int b = blockIdx.x;
  int base = b*1024 + (int)threadIdx.x*4;
  int d0 = (base+0 < N) ? deg[base+0] : 0;
  int d1 = (base+1 < N) ? deg[base+1] : 0;
  int d2 = (base+2 < N) ? deg[base+2] : 0;
  int d3 = (base+3 < N) ? deg[base+3] : 0;
  int s = d0 + d1 + d2 + d3;
  int lane = threadIdx.x & 63, wv = threadIdx.x >> 6;
  int val = s;
  #pragma unroll
  for (int ofs = 1; ofs < 64; ofs <<= 1){
    int tt = __shfl_up(val, ofs, 64);
    if (lane >= ofs) val += tt;
  }
  __shared__ int ws[4];
  if (lane == 63) ws[wv] = val;
  __syncthreads();
  if (threadIdx.x == 0){
    int run = 0;
    #pragma unroll
    for (int w = 0; w < 4; ++w){ int tmp = ws[w]; ws[w] = run; run += tmp; }
  }
  __syncthreads();
  int pre = bsum[b] + ws[wv] + val - s;
  if (base+0 < N){ row_start[base+0] = pre; pre += d0; }
  if (base+1 < N){ row_start[base+1] = pre; pre += d1; }
  if (base+2 < N){ row_start[base+2] = pre; pre += d2; }
  if (base+3 < N){ row_start[base+3] = pre; }
}

__global__ void k_scatter(const int* __restrict__ ei, const float* __restrict__ ea,
                          const int* __restrict__ row_start, const int* __restrict__ rank,
                          int2* __restrict__ csr_se, int E){
  int e = blockIdx.x*blockDim.x + threadIdx.x;
  if (e >= E) return;
  int d = ei[E + e];
  int pos = row_start[d] + rank[e];
  csr_se[pos] = make_int2(ei[e], __float_as_int(ea[e]));
}

// ---------- GAT: 8 lanes/node, 2 heads per lane, 4-unrolled edge loop ----------
__global__ void k_gat(const float* __restrict__ x, const int* __restrict__ row_start,
                      const int2* __restrict__ cse,
                      const float* __restrict__ Wl, const float* __restrict__ bl,
                      const float* __restrict__ Wr, const float* __restrict__ br,
                      const float* __restrict__ We, const float* __restrict__ att,
                      const float* __restrict__ gat_bias,
                      float* __restrict__ h, int N){
  int t = blockIdx.x*blockDim.x + threadIdx.x;
  int n   = t >> 3;
  int sub = t & 7;           // this lane's 2 heads: k-range sub*8 .. sub*8+7
  if (n >= N) return;
  float xd = x[n];
  float wl[8], we[8], at[8], pre[8];
  int k0 = sub*8;
  #pragma unroll
  for (int i = 0; i < 8; ++i){
    int k = k0 + i;
    wl[i] = Wl[k]; we[i] = We[k]; at[i] = att[k];
    pre[i] = bl[k] + fmaf(xd, Wr[k], br[k]);
  }
  int e0 = row_start[n], e1 = row_start[n+1];
  float m[2]  = {-3.4e38f,-3.4e38f};
  float den[2] = {0,0}, S1[2] = {0,0};
  float asum = 0.f;

#define PROC(XS, EAV)                                                        \
  { float xs_ = (XS), ea_ = (EAV);                                           \
    _Pragma("unroll")                                                        \
    for (int hi2 = 0; hi2 < 2; ++hi2){                                       \
      float sc = 0.f;                                                        \
      _Pragma("unroll")                                                      \
      for (int c = 0; c < 4; ++c){                                           \
        int i = hi2*4 + c;                                                   \
        float tt = fmaf(xs_, wl[i], fmaf(ea_, we[i], pre[i]));               \
        tt = (tt > 0.f) ? tt : 0.2f*tt;                                      \
        sc = fmaf(tt, at[i], sc);                                            \
      }                                                                      \
      float nm = fmaxf(m[hi2], sc);                                          \
      float corr = __expf(m[hi2] - nm);                                      \
      float a    = __expf(sc - nm);                                          \
      den[hi2] = den[hi2]*corr + a;                                          \
      S1[hi2]  = S1[hi2] *corr + a*xs_;                                      \
      m[hi2] = nm; } }

  int e = e0;
  for (; e + 3 < e1; e += 4){
    int2 p0 = cse[e], p1 = cse[e+1], p2 = cse[e+2], p3 = cse[e+3];
    float xs0 = x[p0.x], xs1 = x[p1.x], xs2 = x[p2.x], xs3 = x[p3.x];
    float ea0 = __int_as_float(p0.y), ea1 = __int_as_float(p1.y);
    float ea2 = __int_as_float(p2.y), ea3 = __int_as_float(p3.y);
    asum += (ea0 + ea1) + (ea2 + ea3);
    PROC(xs0, ea0);
    PROC(xs1, ea1);
    PROC(xs2, ea2);
    PROC(xs3, ea3);
  }
  for (; e < e1; ++e){
    int2 p0 = cse[e];
    float xs0 = x[p0.x], ea0 = __int_as_float(p0.y);
    asum += ea0;
    PROC(xs0, ea0);
  }
  { // self loop
    float degf = (float)(e1 - e0);
    float eav = asum / fmaxf(degf, 1.0f);
    PROC(xd, eav);
  }
#undef PROC
  #pragma unroll
  for (int hi2 = 0; hi2 < 2; ++hi2){
    float r = S1[hi2] / den[hi2];
    float4 o;
    #pragma unroll
    for (int c = 0; c < 4; ++c){
      int i = hi2*4 + c, k = k0 + i;
      float v = fmaxf(fmaf(wl[i], r, bl[k] + gat_bias[k]), 0.f);
      ((float*)&o)[c] = v;
    }
    *(float4*)(h + (size_t)n*KK + k0 + hi2*4) = o;
  }
}

// ---------- GroupNorm stats: (G x S_SUB) blocks, partial + atomic combine ----------
__global__ void k_gstats_part(const float* __restrict__ h, const int* __restrict__ goff,
                              float* __restrict__ gsum, float* __restrict__ gsum2){
  int g = blockIdx.x, sb = blockIdx.y;
  int s = goff[g], epos = goff[g+1];
  int k = threadIdx.x & 63, slice = threadIdx.x >> 6;
  float sum = 0.f, sum2 = 0.f;
  for (int n = s + sb*4 + slice; n < epos; n += S_SUB*4){
    float v = h[(size_t)n*KK + k];
    sum += v; sum2 += v*v;
  }
  __shared__ float ls[4][KK], ls2[4][KK];
  ls[slice][k] = sum; ls2[slice][k] = sum2;
  __syncthreads();
  if (slice == 0){
    float a  = ls[0][k]+ls[1][k]+ls[2][k]+ls[3][k];
    float b2 = ls2[0][k]+ls2[1][k]+ls2[2][k]+ls2[3][k];
    atomicAdd(&gsum[g*KK + k], a);
    atomicAdd(&gsum2[g*KK + k], b2);
  }
}

// ---------- normalize (fused coefficients) + bf16 copy, float4 ----------
__global__ void k_norm(float* __restrict__ h, unsigned short* __restrict__ hb,
                       const int* __restrict__ batch,
                       const float* __restrict__ gsum, const float* __restrict__ gsum2,
                       const int* __restrict__ goff,
                       const float* __restrict__ gn_w, const float* __restrict__ gn_b,
                       const float* __restrict__ gn_ms, int N){
  int t = blockIdx.x*blockDim.x + threadIdx.x;
  if (t >= N*16) return;
  int n = t >> 4, q = t & 15;
  int b = batch[n];
  float c = fmaxf((float)(goff[b+1] - goff[b]), 1.0f);
  float inv = 1.0f / c;
  float4 hv = *(float4*)(h + (size_t)n*KK + q*4);
  float ov[4];
  #pragma unroll
  for (int i = 0; i < 4; ++i){
    int k = q*4 + i;
    float mean = gsum[b*KK + k]*inv;
    float eh2  = gsum2[b*KK + k]*inv;
    float ms = gn_ms[k];
    float var = eh2 - 2.f*ms*mean*mean + ms*ms*mean*mean;
    float sc = gn_w[k] * __frsqrt_rn(var + 1e-5f);
    float sh = gn_b[k] - sc*mean*ms;
    ov[i] = fmaf(sc, ((float*)&hv)[i], sh);
  }
  *(float4*)(h + (size_t)n*KK + q*4) = make_float4(ov[0], ov[1], ov[2], ov[3]);
  ushort4 bv;
  bv.x = f2bf(ov[0]); bv.y = f2bf(ov[1]); bv.z = f2bf(ov[2]); bv.w = f2bf(ov[3]);
  *(ushort4*)(hb + (size_t)n*KK + q*4) = bv;
}

// ---------- SAGE: ushort4 gather, 8/4/1 tiered unroll, 16 nodes / 256-thread block ----------
__global__ void k_sage(const float* __restrict__ h, const unsigned short* __restrict__ hb,
                       const int* __restrict__ row_start, const int2* __restrict__ cse,
                       const float* __restrict__ Wl, const float* __restrict__ bln,
                       const float* __restrict__ Wr,
                       float* __restrict__ h2, int N){
  __shared__ float snm[16][KK], shn[16][KK];
  const ushort4* hb4 = (const ushort4*)hb;
  int tid = threadIdx.x;
  int u = tid >> 4;
  int q = tid & 15;
  int n = blockIdx.x*16 + u;
  if (n < N){
    int e0 = row_start[n], e1 = row_start[n+1];
    float a0=0.f,a1=0.f,a2=0.f,a3=0.f;
    float b0=0.f,b1=0.f,b2=0.f,b3=0.f;
    int e = e0;
    for (; e + 7 < e1; e += 8){
      int s0 = cse[e].x,   s1 = cse[e+1].x, s2 = cse[e+2].x, s3 = cse[e+3].x;
      int s4 = cse[e+4].x, s5 = cse[e+5].x, s6 = cse[e+6].x, s7 = cse[e+7].x;
      ushort4 v0 = hb4[(size_t)s0*16 + q];
      ushort4 v1 = hb4[(size_t)s1*16 + q];
      ushort4 v2 = hb4[(size_t)s2*16 + q];
      ushort4 v3 = hb4[(size_t)s3*16 + q];
      ushort4 v4 = hb4[(size_t)s4*16 + q];
      ushort4 v5 = hb4[(size_t)s5*16 + q];
      ushort4 v6 = hb4[(size_t)s6*16 + q];
      ushort4 v7 = hb4[(size_t)s7*16 + q];
      a0 += bf2f(v0.x); a1 += bf2f(v0.y); a2 += bf2f(v0.z); a3 += bf2f(v0.w);
      b0 += bf2f(v1.x); b1 += bf2f(v1.y); b2 += bf2f(v1.z); b3 += bf2f(v1.w);
      a0 += bf2f(v2.x); a1 += bf2f(v2.y); a2 += bf2f(v2.z); a3 += bf2f(v2.w);
      b0 += bf2f(v3.x); b1 += bf2f(v3.y); b2 += bf2f(v3.z); b3 += bf2f(v3.w);
      a0 += bf2f(v4.x); a1 += bf2f(v4.y); a2 += bf2f(v4.z); a3 += bf2f(v4.w);
      b0 += bf2f(v5.x); b1 += bf2f(v5.y); b2 += bf2f(v5.z); b3 += bf2f(v5.w);
      a0 += bf2f(v6.x); a1 += bf2f(v6.y); a2 += bf2f(v6.z); a3 += bf2f(v6.w);
      b0 += bf2f(v7.x); b1 += bf2f(v7.y); b2 += bf2f(v7.z); b3 += bf2f(v7.w);
    }
    if (e + 3 < e1){
      int s0 = cse[e].x, s1 = cse[e+1].x, s2 = cse[e+2].x, s3 = cse[e+3].x;
      ushort4 v0 = hb4[(size_t)s0*16 + q];
      ushort4 v1 = hb4[(size_t)s1*16 + q];
      ushort4 v2 = hb4[(size_t)s2*16 + q];
      ushort4 v3 = hb4[(size_t)s3*16 + q];
      a0 += bf2f(v0.x); a1 += bf2f(v0.y); a2 += bf2f(v0.z); a3 += bf2f(v0.w);
      b0 += bf2f(v1.x); b1 += bf2f(v1.y); b2 += bf2f(v1.z); b3 += bf2f(v1.w);
      a0 += bf2f(v2.x); a1 += bf2f(v2.y); a2 += bf2f(v2.z); a3 += bf2f(v2.w);
      b0 += bf2f(v3.x); b1 += bf2f(v3.y); b2 += bf2f(v3.z); b3 += bf2f(v3.w);
      e += 4;
    }
    for (; e < e1; ++e){
      ushort4 v0 = hb4[(size_t)cse[e].x*16 + q];
      a0 += bf2f(v0.x); a1 += bf2f(v0.y); a2 += bf2f(v0.z); a3 += bf2f(v0.w);
    }
    float dg = fmaxf((float)(e1 - e0), 1.0f);
    float inv = 1.0f/dg;
    float4 nm = make_float4((a0+b0)*inv, (a1+b1)*inv, (a2+b2)*inv, (a3+b3)*inv);
    *(float4*)&snm[u][q*4] = nm;
    *(float4*)&shn[u][q*4] = *(const float4*)(h + (size_t)n*KK + q*4);
  }
  __syncthreads();
  int j = tid & 63, u0 = tid >> 6;
  float acc[4];
  #pragma unroll
  for (int p = 0; p < 4; ++p) acc[p] = bln[j];
  for (int k = 0; k < KK; ++k){
    float wlv = Wl[k*KK + j], wrv = Wr[k*KK + j];
    #pragma unroll
    for (int p = 0; p < 4; ++p){
      int un = u0 + p*4;
      acc[p] = fmaf(snm[un][k], wlv, acc[p]);
      acc[p] = fmaf(shn[un][k], wrv, acc[p]);
    }
  }
  #pragma unroll
  for (int p = 0; p < 4; ++p){
    int un = u0 + p*4;
    int nn = blockIdx.x*16 + un;
    if (nn < N) h2[(size_t)nn*KK + j] = fmaxf(acc[p], 0.f);
  }
}

// ---------- pooling: (G x S_SUB) partial blocks + atomic combine ----------
__global__ void k_pool_part(const float* __restrict__ h2, const int* __restrict__ goff,
                            unsigned* __restrict__ gmaxu, float* __restrict__ gsumP){
  int g = blockIdx.x, sb = blockIdx.y;
  int s = goff[g], epos = goff[g+1];
  int k = threadIdx.x & 63, slice = threadIdx.x >> 6;
  float mx = 0.f, sm = 0.f;   // h2 >= 0
  for (int n = s + sb*4 + slice; n < epos; n += S_SUB*4){
    float v = h2[(size_t)n*KK + k];
    mx = fmaxf(mx, v); sm += v;
  }
  __shared__ float lm[4][KK], lsum[4][KK];
  lm[slice][k] = mx; lsum[slice][k] = sm;
  __syncthreads();
  if (slice == 0){
    float m2 = fmaxf(fmaxf(lm[0][k], lm[1][k]), fmaxf(lm[2][k], lm[3][k]));
    float s2 = lsum[0][k]+lsum[1][k]+lsum[2][k]+lsum[3][k];
    atomicMax(&gmaxu[g*KK + k], __float_as_uint(m2));
    atomicAdd(&gsumP[g*KK + k], s2);
  }
}

// ---------- dense layers ----------

__global__ void k_fc1(const unsigned* __restrict__ gmaxu, const float* __restrict__ gsumP,
                      const int* __restrict__ goff,
                      const float* __restrict__ W, const float* __restrict__ b,
                      float* __restrict__ out){
  __shared__ float sin[128];
  int g = blockIdx.y, jt = blockIdx.x;
  int tid = threadIdx.x;
  if (tid < 128){
    float c = fmaxf((float)(goff[g+1] - goff[g]), 1.0f);
    sin[tid] = (tid < 64) ? __uint_as_float(gmaxu[g*64 + tid])
                          : gsumP[g*64 + (tid-64)] / c;
  }
  __syncthreads();
  int j = jt*256 + tid;
  float acc = b[j];
  #pragma unroll 16
  for (int k = 0; k < 128; ++k)
    acc = fmaf(sin[k], W[(size_t)k*2048 + j], acc);
  out[(size_t)g*2048 + j] = fmaxf(acc, 0.f);
}

__global__ void k_fc2a(const float* __restrict__ in, const float* __restrict__ W,
                       float* __restrict__ partial){
  __shared__ float sin[64][128];
  int jt = blockIdx.x, ks = blockIdx.y;
  int k0 = ks*128;
  int tid = threadIdx.x;
  for (int idx = tid; idx < 64*128; idx += 256){
    int g = idx >> 7, k = idx & 127;
    sin[g][k] = in[(size_t)g*2048 + k0 + k];
  }
  __syncthreads();
  int j = tid & 63, gs = tid >> 6;
  const float* Wp = W + (size_t)k0*1024 + jt*64 + j;
  float acc[16];
  #pragma unroll
  for (int p = 0; p < 16; ++p) acc[p] = 0.f;
  for (int k = 0; k < 128; ++k){
    float w = Wp[(size_t)k*1024];
    #pragma unroll
    for (int p = 0; p < 16; ++p)
      acc[p] = fmaf(sin[gs*16 + p][k], w, acc[p]);
  }
  #pragma unroll
  for (int p = 0; p < 16; ++p){
    int g = gs*16 + p;
    partial[((size_t)ks*64 + g)*1024 + jt*64 + j] = acc[p];
  }
}

__global__ void k_fc2red(const float* __restrict__ partial, const float* __restrict__ b,
                         float* __restrict__ out){
  int i = blockIdx.x*blockDim.x + threadIdx.x;
  int g = i >> 10, j = i & 1023;
  float s = b[j];
  #pragma unroll
  for (int ks = 0; ks < 16; ++ks)
    s += partial[((size_t)ks*64 + g)*1024 + j];
  out[i] = fmaxf(s, 0.f);
}

__global__ void k_fc3(const float* __restrict__ in, const float* __restrict__ W,
                      const float* __restrict__ b, float* __restrict__ out, int nOut){
  int w = (blockIdx.x*blockDim.x + threadIdx.x) >> 6;
  int lane = threadIdx.x & 63;
  if (w >= GG*nOut) return;
  int g = w / nOut, j = w - g*nOut;
  const float* row = in + (size_t)g*1024;
  float acc = 0.f;
  #pragma unroll
  for (int k = lane; k < 1024; k += 64)
    acc = fmaf(row[k], W[(size_t)k*nOut + j], acc);
  #pragma unroll
  for (int ofs = 32; ofs >= 1; ofs >>= 1)
    acc += __shfl_down(acc, ofs, 64);
  if (lane == 0) out[w] = acc + b[j];
}

extern "C" void kernel_launch(void* const* d_in, const int* in_sizes, int n_in,
                              void* d_out, int out_size, void* d_ws, size_t ws_size,
                              hipStream_t stream) {
  const float* x        = (const float*)d_in[0];
  const int*   ei       = (const int*)d_in[1];
  const float* ea       = (const float*)d_in[2];
  const int*   batch    = (const int*)d_in[3];
  const float* Wl       = (const float*)d_in[4];
  const float* bl       = (const float*)d_in[5];
  const float* Wr       = (const float*)d_in[6];
  const float* br       = (const float*)d_in[7];
  const float* We       = (const float*)d_in[8];
  const float* att      = (const float*)d_in[9];
  const float* gat_bias = (const float*)d_in[10];
  const float* gn_w     = (const float*)d_in[11];
  const float* gn_b     = (const float*)d_in[12];
  const float* gn_ms    = (const float*)d_in[13];
  const float* sage_Wl  = (const float*)d_in[14];
  const float* sage_bl  = (const float*)d_in[15];
  const float* sage_Wr  = (const float*)d_in[16];
  const float* fc1_W    = (const float*)d_in[17];
  const float* fc1_b    = (const float*)d_in[18];
  const float* fc2_W    = (const float*)d_in[19];
  const float* fc2_b    = (const float*)d_in[20];
  const float* fc3_W    = (const float*)d_in[21];
  const float* fc3_b    = (const float*)d_in[22];

  const int N = in_sizes[0];
  const int E = in_sizes[1] / 2;
  const int NB = (N + 1023) / 1024;

  char* ws = (char*)d_ws;
  size_t off = 0;
  auto alloc = [&](size_t bytes){ void* p = ws + off; off += (bytes + 255) & ~(size_t)255; return p; };

  int*      deg_i  = (int*)alloc((size_t)N*4);        // zeroed
  float*    gsum   = (float*)alloc(GG*KK*4);          // zeroed
  float*    gsum2  = (float*)alloc(GG*KK*4);          // zeroed
  unsigned* gmaxu  = (unsigned*)alloc(GG*KK*4);       // zeroed
  float*    gsumP  = (float*)alloc(GG*KK*4);          // zeroed
  size_t zero_bytes = off;                            // 256-aligned => /16 exact
  int*   rank      = (int*)alloc((size_t)E*4);
  int*   bsum      = (int*)alloc((size_t)NB*4);
  int*   row_start = (int*)alloc((size_t)(N+1)*4);
  int*   goff      = (int*)alloc((GG+1)*4);
  int2*  csr_se    = (int2*)alloc((size_t)E*8);
  float* h         = (float*)alloc((size_t)N*KK*4);
  unsigned short* hb = (unsigned short*)alloc((size_t)N*KK*2);
  float* h2        = (float*)alloc((size_t)N*KK*4);
  float* out1      = (float*)alloc((size_t)GG*2048*4);
  float* out2      = (float*)alloc((size_t)GG*1024*4);
  float* partial   = (float*)alloc((size_t)16*GG*1024*4);
  (void)ws_size; (void)n_in; (void)out_size;

  const int B = 256;
  {
    int nInt4 = (int)(zero_bytes >> 4);
    int blocks = min((nInt4 + B - 1)/B, 256);
    k_zero <<<blocks, B, 0, stream>>>((int4*)d_ws, nInt4, batch, N, goff);
  }
  k_count_rank<<<(E+B-1)/B, B, 0, stream>>>(ei, deg_i, rank, E);
  k_scan1  <<<NB, B, 0, stream>>>(deg_i, bsum, N);
  k_scan2  <<<1, 1024, 0, stream>>>(bsum, row_start + N, NB);
  k_scan3  <<<NB, B, 0, stream>>>(deg_i, bsum, row_start, N);
  k_scatter<<<(E+B-1)/B, B, 0, stream>>>(ei, ea, row_start, rank, csr_se, E);
  k_gat    <<<((size_t)N*8+B-1)/B, B, 0, stream>>>(x, row_start, csr_se,
                                                   Wl, bl, Wr, br, We, att, gat_bias, h, N);
  {
    dim3 grid(GG, S_SUB);
    k_gstats_part<<<grid, 256, 0, stream>>>(h, goff, gsum, gsum2);
  }
  k_norm   <<<((size_t)N*16+B-1)/B, B, 0, stream>>>(h, hb, batch, gsum, gsum2, goff,
                                                    gn_w, gn_b, gn_ms, N);
  k_sage   <<<(N+15)/16, B, 0, stream>>>(h, hb, row_start, csr_se, sage_Wl, sage_bl, sage_Wr, h2, N);
  {
    dim3 grid(GG, S_SUB);
    k_pool_part<<<grid, 256, 0, stream>>>(h2, goff, gmaxu, gsumP);
  }
  {
    dim3 grid(8, GG);
    k_fc1  <<<grid, 256, 0, stream>>>(gmaxu, gsumP, goff, fc1_W, fc1_b, out1);
  }
  {
    dim3 grid(16, 16);
    k_fc2a <<<grid, 256, 0, stream>>>(out1, fc2_W, partial);
  }
  k_fc2red <<<(GG*1024+B-1)/B, B, 0, stream>>>(partial, fc2_b, out2);
  k_fc3    <<<(GG*3*64+B-1)/B, B, 0, stream>>>(out2, fc3_W, fc3_b, (float*)d_out, 3);
}

// Round 12
// 177.987 us; speedup vs baseline: 1.2690x; 1.0769x over previous
//
#include <hip/hip_runtime.h>

#define GG 64
#define HH 16
#define KK 64   // H*C

__device__ __forceinline__ float bf2f(unsigned short u){
  return __uint_as_float(((unsigned)u) << 16);
}
__device__ __forceinline__ unsigned short f2bf(float f){
  unsigned u = __float_as_uint(f);
  unsigned r = u + 0x7fffu + ((u >> 16) & 1u);   // round-to-nearest-even
  return (unsigned short)(r >> 16);
}

// ---------- zero workspace (int4 grid-stride) + group bounds fused ----------
__global__ void k_zero(int4* __restrict__ p, int nInt4,
                       const int* __restrict__ batch, int N, int* __restrict__ goff){
  int t = blockIdx.x*blockDim.x + threadIdx.x;
  for (int i = t; i < nInt4; i += gridDim.x*blockDim.x)
    p[i] = make_int4(0,0,0,0);
  if (blockIdx.x == 0 && threadIdx.x <= GG){
    int g = threadIdx.x;
    int lo = 0, hi = N;
    while (lo < hi){ int mid = (lo+hi) >> 1; if (batch[mid] < g) lo = mid+1; else hi = mid; }
    goff[g] = lo;
  }
}

// ---------- CSR build ----------

__global__ void k_count_rank(const int* __restrict__ ei, int* deg, int* __restrict__ rank, int E){
  int e = blockIdx.x*blockDim.x + threadIdx.x;
  if (e < E) rank[e] = atomicAdd(&deg[ei[E + e]], 1);
}

__global__ void k_scan1(const int* __restrict__ deg, int* __restrict__ bsum, int N){
  int base = blockIdx.x*1024;
  int lim = min(base + 1024, N);
  int s = 0;
  for (int i = base + (int)threadIdx.x; i < lim; i += 256) s += deg[i];
  #pragma unroll
  for (int ofs = 32; ofs >= 1; ofs >>= 1) s += __shfl_down(s, ofs, 64);
  __shared__ int ws[4];
  int lane = threadIdx.x & 63, wv = threadIdx.x >> 6;
  if (lane == 0) ws[wv] = s;
  __syncthreads();
  if (threadIdx.x == 0) bsum[blockIdx.x] = ws[0] + ws[1] + ws[2] + ws[3];
}

__global__ void __launch_bounds__(1024)
k_scan2(int* __restrict__ bsum, int* __restrict__ row_start_N, int NB){
  int t = threadIdx.x;
  int v = (t < NB) ? bsum[t] : 0;
  int lane = t & 63, wv = t >> 6;
  int val = v;
  #pragma unroll
  for (int ofs = 1; ofs < 64; ofs <<= 1){
    int tt = __shfl_up(val, ofs, 64);
    if (lane >= ofs) val += tt;
  }
  __shared__ int ws[16];
  if (lane == 63) ws[wv] = val;
  __syncthreads();
  if (t == 0){
    int run = 0;
    #pragma unroll
    for (int w = 0; w < 16; ++w){ int tmp = ws[w]; ws[w] = run; run += tmp; }
  }
  __syncthreads();
  int excl = ws[wv] + val - v;
  if (t < NB) bsum[t] = excl;
  if (t == NB - 1) *row_start_N = excl + v;
}

__global__ void k_scan3(const int* __restrict__ deg, const int* __restrict__ bsum,
                        int* __restrict__ row_start, int N){
  int b = blockIdx.x;
  int base = b*1024 + (int)threadIdx.x*4;
  int d0 = (base+0 < N) ? deg[base+0] : 0;
  int d1 = (base+1 < N) ? deg[base+1] : 0;
  int d2 = (base+2 < N) ? deg[base+2] : 0;
  int d3 = (base+3 < N) ? deg[base+3] : 0;
  int s = d0 + d1 + d2 + d3;
  int lane = threadIdx.x & 63, wv = threadIdx.x >> 6;
  int val = s;
  #pragma unroll
  for (int ofs = 1; ofs < 64; ofs <<= 1){
    int tt = __shfl_up(val, ofs, 64);
    if (lane >= ofs) val += tt;
  }
  __shared__ int ws[4];
  if (lane == 63) ws[wv] = val;
  __syncthreads();
  if (threadIdx.x == 0){
    int run = 0;
    #pragma unroll
    for (int w = 0; w < 4; ++w){ int tmp = ws[w]; ws[w] = run; run += tmp; }
  }
  __syncthreads();
  int pre = bsum[b] + ws[wv] + val - s;
  if (base+0 < N){ row_start[base+0] = pre; pre += d0; }
  if (base+1 < N){ row_start[base+1] = pre; pre += d1; }
  if (base+2 < N){ row_start[base+2] = pre; pre += d2; }
  if (base+3 < N){ row_start[base+3] = pre; }
}

// scatter packed (src:u16 | bf16(ea):u16) — one 4B store per edge
__global__ void k_scatter(const int* __restrict__ ei, const float* __restrict__ ea,
                          const int* __restrict__ row_start, const int* __restrict__ rank,
                          unsigned* __restrict__ cs, int E){
  int e = blockIdx.x*blockDim.x + threadIdx.x;
  if (e >= E) return;
  int d = ei[E + e];
  int pos = row_start[d] + rank[e];
  cs[pos] = ((unsigned)ei[e] & 0xFFFFu) | ((unsigned)f2bf(ea[e]) << 16);
}

// ---------- GAT: 8 lanes/node, 2 heads/lane + fused GroupNorm stats ----------
__global__ void k_gat(const float* __restrict__ x, const int* __restrict__ row_start,
                      const unsigned* __restrict__ cs,
                      const float* __restrict__ Wl, const float* __restrict__ bl,
                      const float* __restrict__ Wr, const float* __restrict__ br,
                      const float* __restrict__ We, const float* __restrict__ att,
                      const float* __restrict__ gat_bias, const int* __restrict__ batch,
                      float* __restrict__ h, float* __restrict__ gsum, float* __restrict__ gsum2,
                      int N){
  __shared__ float sh[32][KK+1];
  __shared__ int bg[32];
  int tid = threadIdx.x;
  int t = blockIdx.x*blockDim.x + tid;
  int n   = t >> 3;
  int sub = t & 7;           // 2 heads: channels sub*8 .. sub*8+7
  int u   = tid >> 3;        // node slot 0..31
  bool act = (n < N);
  if (sub == 0) bg[u] = act ? batch[n] : -1;
  int k0 = sub*8;
  if (act){
    float xd = x[n];
    float wl[8], we[8], at[8], pre[8];
    #pragma unroll
    for (int i = 0; i < 8; ++i){
      int k = k0 + i;
      wl[i] = Wl[k]; we[i] = We[k]; at[i] = att[k];
      pre[i] = bl[k] + fmaf(xd, Wr[k], br[k]);
    }
    int e0 = row_start[n], e1 = row_start[n+1];
    float m[2]  = {-3.4e38f,-3.4e38f};
    float den[2] = {0,0}, S1[2] = {0,0};
    float asum = 0.f;

#define PROC(XS, EAV)                                                        \
    { float xs_ = (XS), ea_ = (EAV);                                         \
      _Pragma("unroll")                                                      \
      for (int hi2 = 0; hi2 < 2; ++hi2){                                     \
        float sc = 0.f;                                                      \
        _Pragma("unroll")                                                    \
        for (int c = 0; c < 4; ++c){                                         \
          int i = hi2*4 + c;                                                 \
          float tt = fmaf(xs_, wl[i], fmaf(ea_, we[i], pre[i]));             \
          tt = (tt > 0.f) ? tt : 0.2f*tt;                                    \
          sc = fmaf(tt, at[i], sc);                                          \
        }                                                                    \
        float nm = fmaxf(m[hi2], sc);                                        \
        float corr = __expf(m[hi2] - nm);                                    \
        float a    = __expf(sc - nm);                                        \
        den[hi2] = den[hi2]*corr + a;                                        \
        S1[hi2]  = S1[hi2] *corr + a*xs_;                                    \
        m[hi2] = nm; } }

    int e = e0;
    for (; e + 3 < e1; e += 4){
      unsigned w0 = cs[e], w1 = cs[e+1], w2 = cs[e+2], w3 = cs[e+3];
      float xs0 = x[w0 & 0xFFFFu], xs1 = x[w1 & 0xFFFFu];
      float xs2 = x[w2 & 0xFFFFu], xs3 = x[w3 & 0xFFFFu];
      float ea0 = bf2f((unsigned short)(w0 >> 16)), ea1 = bf2f((unsigned short)(w1 >> 16));
      float ea2 = bf2f((unsigned short)(w2 >> 16)), ea3 = bf2f((unsigned short)(w3 >> 16));
      asum += (ea0 + ea1) + (ea2 + ea3);
      PROC(xs0, ea0);
      PROC(xs1, ea1);
      PROC(xs2, ea2);
      PROC(xs3, ea3);
    }
    for (; e < e1; ++e){
      unsigned w0 = cs[e];
      float xs0 = x[w0 & 0xFFFFu], ea0 = bf2f((unsigned short)(w0 >> 16));
      asum += ea0;
      PROC(xs0, ea0);
    }
    { // self loop
      float degf = (float)(e1 - e0);
      float eav = asum / fmaxf(degf, 1.0f);
      PROC(xd, eav);
    }
#undef PROC
    #pragma unroll
    for (int hi2 = 0; hi2 < 2; ++hi2){
      float r = S1[hi2] / den[hi2];
      float4 o;
      #pragma unroll
      for (int c = 0; c < 4; ++c){
        int i = hi2*4 + c, k = k0 + i;
        float v = fmaxf(fmaf(wl[i], r, bl[k] + gat_bias[k]), 0.f);
        ((float*)&o)[c] = v;
        sh[u][k] = v;
      }
      *(float4*)(h + (size_t)n*KK + k0 + hi2*4) = o;
    }
  } else {
    #pragma unroll
    for (int i = 0; i < 8; ++i) sh[u][k0+i] = 0.f;
  }
  __syncthreads();
  // segmented group reduction: ch = tid&63, slice = tid>>6 covers nodes slice*8..+7
  int ch = tid & 63, slice = tid >> 6;
  int cg = -2; float rs = 0.f, rs2 = 0.f;
  for (int uu = slice*8; uu < slice*8 + 8; ++uu){
    int g = bg[uu];
    if (g != cg){
      if (cg >= 0){ atomicAdd(&gsum[cg*KK + ch], rs); atomicAdd(&gsum2[cg*KK + ch], rs2); }
      cg = g; rs = 0.f; rs2 = 0.f;
    }
    if (g >= 0){ float v = sh[uu][ch]; rs += v; rs2 += v*v; }
  }
  if (cg >= 0){ atomicAdd(&gsum[cg*KK + ch], rs); atomicAdd(&gsum2[cg*KK + ch], rs2); }
}

// ---------- normalize (fused coefficients) + bf16 copy, float4 ----------
__global__ void k_norm(float* __restrict__ h, unsigned short* __restrict__ hb,
                       const int* __restrict__ batch,
                       const float* __restrict__ gsum, const float* __restrict__ gsum2,
                       const int* __restrict__ goff,
                       const float* __restrict__ gn_w, const float* __restrict__ gn_b,
                       const float* __restrict__ gn_ms, int N){
  int t = blockIdx.x*blockDim.x + threadIdx.x;
  if (t >= N*16) return;
  int n = t >> 4, q = t & 15;
  int b = batch[n];
  float c = fmaxf((float)(goff[b+1] - goff[b]), 1.0f);
  float inv = 1.0f / c;
  float4 hv = *(float4*)(h + (size_t)n*KK + q*4);
  float ov[4];
  #pragma unroll
  for (int i = 0; i < 4; ++i){
    int k = q*4 + i;
    float mean = gsum[b*KK + k]*inv;
    float eh2  = gsum2[b*KK + k]*inv;
    float ms = gn_ms[k];
    float var = eh2 - 2.f*ms*mean*mean + ms*ms*mean*mean;
    float sc = gn_w[k] * __frsqrt_rn(var + 1e-5f);
    float sh = gn_b[k] - sc*mean*ms;
    ov[i] = fmaf(sc, ((float*)&hv)[i], sh);
  }
  *(float4*)(h + (size_t)n*KK + q*4) = make_float4(ov[0], ov[1], ov[2], ov[3]);
  ushort4 bv;
  bv.x = f2bf(ov[0]); bv.y = f2bf(ov[1]); bv.z = f2bf(ov[2]); bv.w = f2bf(ov[3]);
  *(ushort4*)(hb + (size_t)n*KK + q*4) = bv;
}

// ---------- SAGE + fused pooling: 16 nodes / 256-thread block ----------
__global__ void k_sage(const float* __restrict__ h, const unsigned short* __restrict__ hb,
                       const int* __restrict__ row_start, const unsigned* __restrict__ cs,
                       const float* __restrict__ Wl, const float* __restrict__ bln,
                       const float* __restrict__ Wr, const int* __restrict__ batch,
                       unsigned* __restrict__ gmaxu, float* __restrict__ gsumP, int N){
  __shared__ float snm[16][KK], shn[16][KK];
  __shared__ int bg[16];
  const ushort4* hb4 = (const ushort4*)hb;
  int tid = threadIdx.x;
  int u = tid >> 4;
  int q = tid & 15;
  int n = blockIdx.x*16 + u;
  if (tid < 16) bg[tid] = (blockIdx.x*16 + tid < N) ? batch[blockIdx.x*16 + tid] : -1;
  if (n < N){
    int e0 = row_start[n], e1 = row_start[n+1];
    float a0=0.f,a1=0.f,a2=0.f,a3=0.f;
    float b0=0.f,b1=0.f,b2=0.f,b3=0.f;
    int e = e0;
    for (; e + 7 < e1; e += 8){
      int s0 = cs[e]   & 0xFFFF, s1 = cs[e+1] & 0xFFFF, s2 = cs[e+2] & 0xFFFF, s3 = cs[e+3] & 0xFFFF;
      int s4 = cs[e+4] & 0xFFFF, s5 = cs[e+5] & 0xFFFF, s6 = cs[e+6] & 0xFFFF, s7 = cs[e+7] & 0xFFFF;
      ushort4 v0 = hb4[(size_t)s0*16 + q];
      ushort4 v1 = hb4[(size_t)s1*16 + q];
      ushort4 v2 = hb4[(size_t)s2*16 + q];
      ushort4 v3 = hb4[(size_t)s3*16 + q];
      ushort4 v4 = hb4[(size_t)s4*16 + q];
      ushort4 v5 = hb4[(size_t)s5*16 + q];
      ushort4 v6 = hb4[(size_t)s6*16 + q];
      ushort4 v7 = hb4[(size_t)s7*16 + q];
      a0 += bf2f(v0.x); a1 += bf2f(v0.y); a2 += bf2f(v0.z); a3 += bf2f(v0.w);
      b0 += bf2f(v1.x); b1 += bf2f(v1.y); b2 += bf2f(v1.z); b3 += bf2f(v1.w);
      a0 += bf2f(v2.x); a1 += bf2f(v2.y); a2 += bf2f(v2.z); a3 += bf2f(v2.w);
      b0 += bf2f(v3.x); b1 += bf2f(v3.y); b2 += bf2f(v3.z); b3 += bf2f(v3.w);
      a0 += bf2f(v4.x); a1 += bf2f(v4.y); a2 += bf2f(v4.z); a3 += bf2f(v4.w);
      b0 += bf2f(v5.x); b1 += bf2f(v5.y); b2 += bf2f(v5.z); b3 += bf2f(v5.w);
      a0 += bf2f(v6.x); a1 += bf2f(v6.y); a2 += bf2f(v6.z); a3 += bf2f(v6.w);
      b0 += bf2f(v7.x); b1 += bf2f(v7.y); b2 += bf2f(v7.z); b3 += bf2f(v7.w);
    }
    if (e + 3 < e1){
      int s0 = cs[e] & 0xFFFF, s1 = cs[e+1] & 0xFFFF, s2 = cs[e+2] & 0xFFFF, s3 = cs[e+3] & 0xFFFF;
      ushort4 v0 = hb4[(size_t)s0*16 + q];
      ushort4 v1 = hb4[(size_t)s1*16 + q];
      ushort4 v2 = hb4[(size_t)s2*16 + q];
      ushort4 v3 = hb4[(size_t)s3*16 + q];
      a0 += bf2f(v0.x); a1 += bf2f(v0.y); a2 += bf2f(v0.z); a3 += bf2f(v0.w);
      b0 += bf2f(v1.x); b1 += bf2f(v1.y); b2 += bf2f(v1.z); b3 += bf2f(v1.w);
      a0 += bf2f(v2.x); a1 += bf2f(v2.y); a2 += bf2f(v2.z); a3 += bf2f(v2.w);
      b0 += bf2f(v3.x); b1 += bf2f(v3.y); b2 += bf2f(v3.z); b3 += bf2f(v3.w);
      e += 4;
    }
    for (; e < e1; ++e){
      ushort4 v0 = hb4[(size_t)(cs[e] & 0xFFFF)*16 + q];
      a0 += bf2f(v0.x); a1 += bf2f(v0.y); a2 += bf2f(v0.z); a3 += bf2f(v0.w);
    }
    float dg = fmaxf((float)(e1 - e0), 1.0f);
    float inv = 1.0f/dg;
    float4 nm = make_float4((a0+b0)*inv, (a1+b1)*inv, (a2+b2)*inv, (a3+b3)*inv);
    *(float4*)&snm[u][q*4] = nm;
    *(float4*)&shn[u][q*4] = *(const float4*)(h + (size_t)n*KK + q*4);
  }
  __syncthreads();
  int j = tid & 63, u0 = tid >> 6;
  float acc[4];
  #pragma unroll
  for (int p = 0; p < 4; ++p) acc[p] = bln[j];
  for (int k = 0; k < KK; ++k){
    float wlv = Wl[k*KK + j], wrv = Wr[k*KK + j];
    #pragma unroll
    for (int p = 0; p < 4; ++p){
      int un = u0 + p*4;
      acc[p] = fmaf(snm[un][k], wlv, acc[p]);
      acc[p] = fmaf(shn[un][k], wrv, acc[p]);
    }
  }
  __syncthreads();   // all matmul reads of snm complete before overwrite
  #pragma unroll
  for (int p = 0; p < 4; ++p)
    snm[u0 + p*4][j] = fmaxf(acc[p], 0.f);
  __syncthreads();
  // segmented pooling over the block's 16 nodes (threads 0..63, one per channel)
  if (tid < 64){
    int cg = -2; float rmax = 0.f, rsum = 0.f;
    for (int uu = 0; uu < 16; ++uu){
      int g = bg[uu];
      if (g != cg){
        if (cg >= 0){
          atomicMax(&gmaxu[cg*KK + tid], __float_as_uint(rmax));
          atomicAdd(&gsumP[cg*KK + tid], rsum);
        }
        cg = g; rmax = 0.f; rsum = 0.f;
      }
      if (g >= 0){ float v = snm[uu][tid]; rmax = fmaxf(rmax, v); rsum += v; }
    }
    if (cg >= 0){
      atomicMax(&gmaxu[cg*KK + tid], __float_as_uint(rmax));
      atomicAdd(&gsumP[cg*KK + tid], rsum);
    }
  }
}

// ---------- dense layers ----------

__global__ void k_fc1(const unsigned* __restrict__ gmaxu, const float* __restrict__ gsumP,
                      const int* __restrict__ goff,
                      const float* __restrict__ W, const float* __restrict__ b,
                      float* __restrict__ out){
  __shared__ float sin[128];
  int g = blockIdx.y, jt = blockIdx.x;
  int tid = threadIdx.x;
  if (tid < 128){
    float c = fmaxf((float)(goff[g+1] - goff[g]), 1.0f);
    sin[tid] = (tid < 64) ? __uint_as_float(gmaxu[g*64 + tid])
                          : gsumP[g*64 + (tid-64)] / c;
  }
  __syncthreads();
  int j = jt*256 + tid;
  float acc = b[j];
  #pragma unroll 16
  for (int k = 0; k < 128; ++k)
    acc = fmaf(sin[k], W[(size_t)k*2048 + j], acc);
  out[(size_t)g*2048 + j] = fmaxf(acc, 0.f);
}

__global__ void k_fc2a(const float* __restrict__ in, const float* __restrict__ W,
                       float* __restrict__ partial){
  __shared__ float sin[64][128];
  int jt = blockIdx.x, ks = blockIdx.y;
  int k0 = ks*128;
  int tid = threadIdx.x;
  for (int idx = tid; idx < 64*128; idx += 256){
    int g = idx >> 7, k = idx & 127;
    sin[g][k] = in[(size_t)g*2048 + k0 + k];
  }
  __syncthreads();
  int j = tid & 63, gs = tid >> 6;
  const float* Wp = W + (size_t)k0*1024 + jt*64 + j;
  float acc[16];
  #pragma unroll
  for (int p = 0; p < 16; ++p) acc[p] = 0.f;
  for (int k = 0; k < 128; ++k){
    float w = Wp[(size_t)k*1024];
    #pragma unroll
    for (int p = 0; p < 16; ++p)
      acc[p] = fmaf(sin[gs*16 + p][k], w, acc[p]);
  }
  #pragma unroll
  for (int p = 0; p < 16; ++p){
    int g = gs*16 + p;
    partial[((size_t)ks*64 + g)*1024 + jt*64 + j] = acc[p];
  }
}

__global__ void k_fc2red(const float* __restrict__ partial, const float* __restrict__ b,
                         float* __restrict__ out){
  int i = blockIdx.x*blockDim.x + threadIdx.x;
  int g = i >> 10, j = i & 1023;
  float s = b[j];
  #pragma unroll
  for (int ks = 0; ks < 16; ++ks)
    s += partial[((size_t)ks*64 + g)*1024 + j];
  out[i] = fmaxf(s, 0.f);
}

__global__ void k_fc3(const float* __restrict__ in, const float* __restrict__ W,
                      const float* __restrict__ b, float* __restrict__ out, int nOut){
  int w = (blockIdx.x*blockDim.x + threadIdx.x) >> 6;
  int lane = threadIdx.x & 63;
  if (w >= GG*nOut) return;
  int g = w / nOut, j = w - g*nOut;
  const float* row = in + (size_t)g*1024;
  float acc = 0.f;
  #pragma unroll
  for (int k = lane; k < 1024; k += 64)
    acc = fmaf(row[k], W[(size_t)k*nOut + j], acc);
  #pragma unroll
  for (int ofs = 32; ofs >= 1; ofs >>= 1)
    acc += __shfl_down(acc, ofs, 64);
  if (lane == 0) out[w] = acc + b[j];
}

extern "C" void kernel_launch(void* const* d_in, const int* in_sizes, int n_in,
                              void* d_out, int out_size, void* d_ws, size_t ws_size,
                              hipStream_t stream) {
  const float* x        = (const float*)d_in[0];
  const int*   ei       = (const int*)d_in[1];
  const float* ea       = (const float*)d_in[2];
  const int*   batch    = (const int*)d_in[3];
  const float* Wl       = (const float*)d_in[4];
  const float* bl       = (const float*)d_in[5];
  const float* Wr       = (const float*)d_in[6];
  const float* br       = (const float*)d_in[7];
  const float* We       = (const float*)d_in[8];
  const float* att      = (const float*)d_in[9];
  const float* gat_bias = (const float*)d_in[10];
  const float* gn_w     = (const float*)d_in[11];
  const float* gn_b     = (const float*)d_in[12];
  const float* gn_ms    = (const float*)d_in[13];
  const float* sage_Wl  = (const float*)d_in[14];
  const float* sage_bl  = (const float*)d_in[15];
  const float* sage_Wr  = (const float*)d_in[16];
  const float* fc1_W    = (const float*)d_in[17];
  const float* fc1_b    = (const float*)d_in[18];
  const float* fc2_W    = (const float*)d_in[19];
  const float* fc2_b    = (const float*)d_in[20];
  const float* fc3_W    = (const float*)d_in[21];
  const float* fc3_b    = (const float*)d_in[22];

  const int N = in_sizes[0];
  const int E = in_sizes[1] / 2;
  const int NB = (N + 1023) / 1024;

  char* ws = (char*)d_ws;
  size_t off = 0;
  auto alloc = [&](size_t bytes){ void* p = ws + off; off += (bytes + 255) & ~(size_t)255; return p; };

  int*      deg_i  = (int*)alloc((size_t)N*4);        // zeroed
  float*    gsum   = (float*)alloc(GG*KK*4);          // zeroed
  float*    gsum2  = (float*)alloc(GG*KK*4);          // zeroed
  unsigned* gmaxu  = (unsigned*)alloc(GG*KK*4);       // zeroed
  float*    gsumP  = (float*)alloc(GG*KK*4);          // zeroed
  size_t zero_bytes = off;                            // 256-aligned => /16 exact
  int*   rank      = (int*)alloc((size_t)E*4);
  int*   bsum      = (int*)alloc((size_t)NB*4);
  int*   row_start = (int*)alloc((size_t)(N+1)*4);
  int*   goff      = (int*)alloc((GG+1)*4);
  unsigned* csp    = (unsigned*)alloc((size_t)E*4);
  float* h         = (float*)alloc((size_t)N*KK*4);
  unsigned short* hb = (unsigned short*)alloc((size_t)N*KK*2);
  float* out1      = (float*)alloc((size_t)GG*2048*4);
  float* out2      = (float*)alloc((size_t)GG*1024*4);
  float* partial   = (float*)alloc((size_t)16*GG*1024*4);
  (void)ws_size; (void)n_in; (void)out_size;

  const int B = 256;
  {
    int nInt4 = (int)(zero_bytes >> 4);
    int blocks = min((nInt4 + B - 1)/B, 256);
    k_zero <<<blocks, B, 0, stream>>>((int4*)d_ws, nInt4, batch, N, goff);
  }
  k_count_rank<<<(E+B-1)/B, B, 0, stream>>>(ei, deg_i, rank, E);
  k_scan1  <<<NB, B, 0, stream>>>(deg_i, bsum, N);
  k_scan2  <<<1, 1024, 0, stream>>>(bsum, row_start + N, NB);
  k_scan3  <<<NB, B, 0, stream>>>(deg_i, bsum, row_start, N);
  k_scatter<<<(E+B-1)/B, B, 0, stream>>>(ei, ea, row_start, rank, csp, E);
  k_gat    <<<((size_t)N*8+B-1)/B, B, 0, stream>>>(x, row_start, csp,
                                                   Wl, bl, Wr, br, We, att, gat_bias,
                                                   batch, h, gsum, gsum2, N);
  k_norm   <<<((size_t)N*16+B-1)/B, B, 0, stream>>>(h, hb, batch, gsum, gsum2, goff,
                                                    gn_w, gn_b, gn_ms, N);
  k_sage   <<<(N+15)/16, B, 0, stream>>>(h, hb, row_start, csp, sage_Wl, sage_bl, sage_Wr,
                                         batch, gmaxu, gsumP, N);
  {
    dim3 grid(8, GG);
    k_fc1  <<<grid, 256, 0, stream>>>(gmaxu, gsumP, goff, fc1_W, fc1_b, out1);
  }
  {
    dim3 grid(16, 16);
    k_fc2a <<<grid, 256, 0, stream>>>(out1, fc2_W, partial);
  }
  k_fc2red <<<(GG*1024+B-1)/B, B, 0, stream>>>(partial, fc2_b, out2);
  k_fc3    <<<(GG*3*64+B-1)/B, B, 0, stream>>>(out2, fc3_W, fc3_b, (float*)d_out, 3);
}